// Round 1
// baseline (944.658 us; speedup 1.0000x reference)
//
#include <hip/hip_runtime.h>
#include <stdint.h>

typedef unsigned short u16;
typedef __bf16 bf16x8 __attribute__((ext_vector_type(8)));
typedef float f32x4 __attribute__((ext_vector_type(4)));
typedef unsigned short u16x8 __attribute__((ext_vector_type(8)));
typedef unsigned short u16x4 __attribute__((ext_vector_type(4)));

__device__ __forceinline__ float b2f(u16 b) {
    return __uint_as_float(((unsigned)b) << 16);
}
__device__ __forceinline__ u16 f2b(float f) {
    unsigned u = __float_as_uint(f);
    unsigned r = (u + 0x7fffu + ((u >> 16) & 1u)) >> 16;  // RNE
    return (u16)r;
}

#define GLDS16(g, l) __builtin_amdgcn_global_load_lds(                        \
    (const __attribute__((address_space(1))) void*)(g),                       \
    (__attribute__((address_space(3))) void*)(l), 16, 0, 0)

// ---------------------------------------------------------------------------
// C = epilogue(A @ Bt^T):  A[M,K] bf16 row-major (lda=K), Bt[N,K] bf16
// row-major (ldb=K), C[M,N] (ldc=N).  epilogue: v=(acc+bias)*scale; relu;
// +res(fp32); store bf16 or fp32.
// 128x128 tile, BK=64, 4 waves (2x2), mfma_f32_16x16x32_bf16, m97 structure.
// ---------------------------------------------------------------------------
template<bool HAS_BIAS, bool RELU, bool HAS_RES, bool OUT_BF16>
__global__ __launch_bounds__(256) void gemm_bt(
    const u16* __restrict__ A, const u16* __restrict__ Bt,
    const float* __restrict__ bias, const float* __restrict__ res,
    void* __restrict__ Cout, int M, int N, int K, float scale)
{
    __shared__ u16 sA[128 * 64];
    __shared__ u16 sB[128 * 64];
    const int t    = threadIdx.x;
    const int lane = t & 63;
    const int wid  = t >> 6;
    const int wm   = wid >> 1, wn = wid & 1;
    const int lr   = lane & 15, lk = lane >> 4;
    const long m0  = (long)blockIdx.y * 128;
    const long n0  = (long)blockIdx.x * 128;

    f32x4 acc[4][4];
    #pragma unroll
    for (int i = 0; i < 4; ++i)
        #pragma unroll
        for (int j = 0; j < 4; ++j)
            #pragma unroll
            for (int r = 0; r < 4; ++r) acc[i][j][r] = 0.0f;

    // staging: chunk c = it*256 + t covers LDS bytes [c*16, c*16+16)
    // = logical (row = c>>3, col8 = (c&7)*8) of the 128x64 bf16 tile.
    const u16* gA = A  + (m0 + (t >> 3)) * (long)K + (t & 7) * 8;
    const u16* gB = Bt + (n0 + (t >> 3)) * (long)K + (t & 7) * 8;
    u16* lA = sA + (t & ~63) * 8;   // wave-uniform base; HW adds lane*16B
    u16* lB = sB + (t & ~63) * 8;

    for (int k0 = 0; k0 < K; k0 += 64) {
        #pragma unroll
        for (int it = 0; it < 4; ++it) {
            GLDS16(gA + (long)it * 32 * K + k0, lA + it * 2048);
            GLDS16(gB + (long)it * 32 * K + k0, lB + it * 2048);
        }
        __syncthreads();
        #pragma unroll
        for (int ks = 0; ks < 2; ++ks) {
            bf16x8 af[4], bfr[4];
            #pragma unroll
            for (int i = 0; i < 4; ++i) {
                af[i]  = *(const bf16x8*)(sA + (wm * 64 + i * 16 + lr) * 64 + ks * 32 + lk * 8);
                bfr[i] = *(const bf16x8*)(sB + (wn * 64 + i * 16 + lr) * 64 + ks * 32 + lk * 8);
            }
            #pragma unroll
            for (int i = 0; i < 4; ++i)
                #pragma unroll
                for (int j = 0; j < 4; ++j)
                    acc[i][j] = __builtin_amdgcn_mfma_f32_16x16x32_bf16(
                        af[i], bfr[j], acc[i][j], 0, 0, 0);
        }
        __syncthreads();
    }

    // epilogue: C/D layout col = lane&15, row = (lane>>4)*4 + reg  [m89]
    const long crow0 = m0 + wm * 64;
    const long ccol0 = n0 + wn * 64;
    #pragma unroll
    for (int i = 0; i < 4; ++i) {
        #pragma unroll
        for (int j = 0; j < 4; ++j) {
            const long col = ccol0 + j * 16 + lr;
            float bv_ = 0.0f;
            if (HAS_BIAS) bv_ = bias[col];
            #pragma unroll
            for (int r = 0; r < 4; ++r) {
                const long row = crow0 + i * 16 + lk * 4 + r;
                float v = acc[i][j][r];
                if (HAS_BIAS) v += bv_;
                v *= scale;
                if (RELU) v = fmaxf(v, 0.0f);
                if (HAS_RES) v += res[row * (long)N + col];
                if (OUT_BF16)
                    ((u16*)Cout)[row * (long)N + col] = f2b(v);
                else
                    ((float*)Cout)[row * (long)N + col] = v;
            }
        }
    }
}

// ---------------------------------------------------------------------------
__global__ __launch_bounds__(256) void cvt_f32_bf16(
    const float* __restrict__ in, u16* __restrict__ out, long n)
{
    long i = ((long)blockIdx.x * 256 + threadIdx.x) * 4;
    if (i >= n) return;
    float4 f = *(const float4*)(in + i);
    u16x4 o;
    o[0] = f2b(f.x); o[1] = f2b(f.y); o[2] = f2b(f.z); o[3] = f2b(f.w);
    *(u16x4*)(out + i) = o;
}

// out[c*R + r] = in[r*C + c], out bf16.  block (32,8), grid (C/32, R/32).
template<bool IN_F32>
__global__ __launch_bounds__(256) void transpose_to_bf16(
    const void* __restrict__ in_, u16* __restrict__ out, int R, int C)
{
    __shared__ float tile[32][33];
    const int bx = blockIdx.x * 32;   // col base
    const int by = blockIdx.y * 32;   // row base
    const int tx = threadIdx.x, ty = threadIdx.y;
    #pragma unroll
    for (int i = 0; i < 32; i += 8) {
        const long r = by + ty + i, c = bx + tx;
        float f = IN_F32 ? ((const float*)in_)[r * (long)C + c]
                         : b2f(((const u16*)in_)[r * (long)C + c]);
        tile[ty + i][tx] = f;
    }
    __syncthreads();
    #pragma unroll
    for (int i = 0; i < 32; i += 8)
        out[(long)(bx + ty + i) * R + by + tx] = f2b(tile[tx][ty + i]);
}

// in-place row softmax over n=4096 bf16 elements; one block per row.
__global__ __launch_bounds__(256) void softmax_rows(u16* __restrict__ P, int n)
{
    const int t = threadIdx.x;
    const int lane = t & 63, w = t >> 6;
    u16* row = P + (long)blockIdx.x * n;
    u16x8 a = *(const u16x8*)(row + t * 16);
    u16x8 b = *(const u16x8*)(row + t * 16 + 8);
    float v[16];
    #pragma unroll
    for (int i = 0; i < 8; ++i) { v[i] = b2f(a[i]); v[8 + i] = b2f(b[i]); }

    float mx = v[0];
    #pragma unroll
    for (int i = 1; i < 16; ++i) mx = fmaxf(mx, v[i]);
    #pragma unroll
    for (int o = 32; o > 0; o >>= 1) mx = fmaxf(mx, __shfl_xor(mx, o));
    __shared__ float red[8];
    if (lane == 0) red[w] = mx;
    __syncthreads();
    mx = fmaxf(fmaxf(red[0], red[1]), fmaxf(red[2], red[3]));

    float s = 0.0f;
    #pragma unroll
    for (int i = 0; i < 16; ++i) { v[i] = __expf(v[i] - mx); s += v[i]; }
    #pragma unroll
    for (int o = 32; o > 0; o >>= 1) s += __shfl_xor(s, o);
    if (lane == 0) red[4 + w] = s;
    __syncthreads();
    s = red[4] + red[5] + red[6] + red[7];
    const float inv = 1.0f / s;

    #pragma unroll
    for (int i = 0; i < 8; ++i) { a[i] = f2b(v[i] * inv); b[i] = f2b(v[8 + i] * inv); }
    *(u16x8*)(row + t * 16)     = a;
    *(u16x8*)(row + t * 16 + 8) = b;
}

// ---------------------------------------------------------------------------
extern "C" void kernel_launch(void* const* d_in, const int* in_sizes, int n_in,
                              void* d_out, int out_size, void* d_ws, size_t ws_size,
                              hipStream_t stream)
{
    (void)in_sizes; (void)n_in; (void)out_size; (void)ws_size;
    const float* x  = (const float*)d_in[0];
    const float* Wq = (const float*)d_in[1];
    const float* bq = (const float*)d_in[2];
    const float* Wk = (const float*)d_in[3];
    const float* bk = (const float*)d_in[4];
    const float* Wv = (const float*)d_in[5];
    const float* bv = (const float*)d_in[6];
    const float* W1 = (const float*)d_in[7];
    const float* b1 = (const float*)d_in[8];
    const float* W2 = (const float*)d_in[9];
    const float* b2 = (const float*)d_in[10];
    float* out = (float*)d_out;

    const int  B = 4, S = 4096, D = 1024;
    const long SD = (long)S * D;          // 4 Mi
    const long BSD = (long)B * SD;        // 16 Mi

    // workspace layout (bf16 = u16), total ~202 MB:
    u16* xb = (u16*)d_ws;       // [B*S, D]  x in bf16
    u16* Wt = xb + BSD;         // 5 x [D, D]  W^T bf16 (q,k,v,1,2)
    u16* Qb = Wt + 5L * D * D;  // [B*S, D]  Q  (later: h)
    u16* Kb = Qb + BSD;         // [B*S, D]  K  (later: x_res, per batch)
    u16* Vb = Kb + BSD;         // [B*S, D]  V
    u16* Vt = Vb + BSD;         // B x [D, S]  V^T
    u16* Pb = Vt + BSD;         // [S, S]  scores/P, reused per batch

    // 1. x -> bf16
    cvt_f32_bf16<<<dim3((unsigned)(BSD / 4 / 256)), 256, 0, stream>>>(x, xb, BSD);

    // 2. weight transpose+convert: Wt_i[n][k] = W_i[k][n]
    dim3 tb(32, 8);
    transpose_to_bf16<true><<<dim3(D / 32, D / 32), tb, 0, stream>>>(Wq, Wt + 0L * D * D, D, D);
    transpose_to_bf16<true><<<dim3(D / 32, D / 32), tb, 0, stream>>>(Wk, Wt + 1L * D * D, D, D);
    transpose_to_bf16<true><<<dim3(D / 32, D / 32), tb, 0, stream>>>(Wv, Wt + 2L * D * D, D, D);
    transpose_to_bf16<true><<<dim3(D / 32, D / 32), tb, 0, stream>>>(W1, Wt + 3L * D * D, D, D);
    transpose_to_bf16<true><<<dim3(D / 32, D / 32), tb, 0, stream>>>(W2, Wt + 4L * D * D, D, D);

    // 3. QKV projections: [B*S,D] @ [D,D] + bias -> bf16
    dim3 gq(D / 128, (B * S) / 128);   // (8, 128)
    gemm_bt<true, false, false, true><<<gq, 256, 0, stream>>>(xb, Wt + 0L * D * D, bq, nullptr, Qb, B * S, D, D, 1.0f);
    gemm_bt<true, false, false, true><<<gq, 256, 0, stream>>>(xb, Wt + 1L * D * D, bk, nullptr, Kb, B * S, D, D, 1.0f);
    gemm_bt<true, false, false, true><<<gq, 256, 0, stream>>>(xb, Wt + 2L * D * D, bv, nullptr, Vb, B * S, D, D, 1.0f);

    // 4. V^T per batch: [S,D] -> [D,S]
    for (int b = 0; b < B; ++b)
        transpose_to_bf16<false><<<dim3(D / 32, S / 32), tb, 0, stream>>>(Vb + b * SD, Vt + b * SD, S, D);

    // 5. attention per batch (scores buffer reused)
    for (int b = 0; b < B; ++b) {
        // scores = Q K^T / 32 -> bf16 [S,S]
        gemm_bt<false, false, false, true><<<dim3(S / 128, S / 128), 256, 0, stream>>>(
            Qb + b * SD, Kb + b * SD, nullptr, nullptr, Pb, S, S, D, 0.03125f);
        softmax_rows<<<S, 256, 0, stream>>>(Pb, S);
        // x_res = x + P @ V   (written into Kb region for batch b)
        gemm_bt<false, false, true, true><<<dim3(D / 128, S / 128), 256, 0, stream>>>(
            Pb, Vt + b * SD, nullptr, x + b * SD, Kb + b * SD, S, D, S, 1.0f);
    }

    // 6. FFN: h = relu(x_res @ W1 + b1) -> Qb;  out = 2*(h @ W2 + b2) fp32
    gemm_bt<true, true,  false, true ><<<gq, 256, 0, stream>>>(Kb, Wt + 3L * D * D, b1, nullptr, Qb, B * S, D, D, 1.0f);
    gemm_bt<true, false, false, false><<<gq, 256, 0, stream>>>(Qb, Wt + 4L * D * D, b2, nullptr, out, B * S, D, D, 2.0f);
}